// Round 2
// baseline (740.824 us; speedup 1.0000x reference)
//
#include <hip/hip_runtime.h>
#include <math.h>

#define NN 50000
#define EE 800000
#define DFi 8
#define DHc 32
#define Hh 4
#define HCc 128
#define DEe 4
#define DDd 256
#define DOo 4

// ---------------- edge-index dtype detect + convert ----------------
__global__ void detect_kernel(const unsigned int* __restrict__ w, int nwords, int* __restrict__ flag) {
    unsigned int acc = 0;
    for (int i = 2 * threadIdx.x + 1; i < nwords; i += 512) acc |= w[i];
    if (acc) atomicOr(flag, 1);
}

__global__ void convert_kernel(const void* __restrict__ buf, const int* __restrict__ flag,
                               int* __restrict__ out, int n) {
    int i = blockIdx.x * 256 + threadIdx.x;
    if (i >= n) return;
    if (*flag) out[i] = ((const int*)buf)[i];                 // int32 input
    else       out[i] = (int)(((const long long*)buf)[i]);    // int64 input
}

// ---------------- CSR build ----------------
__global__ void count_kernel(const int* __restrict__ EI, int* __restrict__ counts) {
    int e = blockIdx.x * 256 + threadIdx.x;
    if (e >= EE) return;
    atomicAdd(&counts[EI[EE + e]], 1);
}

__global__ void scanA_kernel(const int* __restrict__ counts, int* __restrict__ roff,
                             int* __restrict__ bsum, int M) {
    __shared__ int sd[256];
    int t = threadIdx.x;
    int idx = blockIdx.x * 256 + t;
    int v = (idx < M) ? counts[idx] : 0;
    sd[t] = v;
    __syncthreads();
    for (int off = 1; off < 256; off <<= 1) {
        int x = (t >= off) ? sd[t - off] : 0;
        __syncthreads();
        sd[t] += x;
        __syncthreads();
    }
    if (idx < M) roff[idx] = sd[t] - v;      // exclusive
    if (t == 255) bsum[blockIdx.x] = sd[255];
}

__global__ void scanB_kernel(const int* __restrict__ bsum, int* __restrict__ boff, int nb) {
    __shared__ int sd[256];
    int t = threadIdx.x;
    int v = (t < nb) ? bsum[t] : 0;
    sd[t] = v;
    __syncthreads();
    for (int off = 1; off < 256; off <<= 1) {
        int x = (t >= off) ? sd[t - off] : 0;
        __syncthreads();
        sd[t] += x;
        __syncthreads();
    }
    boff[t] = sd[t] - v;                     // exclusive
}

__global__ void scanC_kernel(int* __restrict__ roff, const int* __restrict__ boff, int M) {
    int idx = blockIdx.x * 256 + threadIdx.x;
    if (idx < M) roff[idx] += boff[idx >> 8];
}

__global__ void fill_kernel(const int* __restrict__ EI, const int* __restrict__ roff,
                            int* __restrict__ cursor, int* __restrict__ col, int* __restrict__ eidp) {
    int e = blockIdx.x * 256 + threadIdx.x;
    if (e >= EE) return;
    int d = EI[EE + e];
    int pos = atomicAdd(&cursor[d], 1);
    int w = roff[d] + pos;
    col[w] = EI[e];
    eidp[w] = e;
}

// deterministic order within each segment: insertion sort by edge id
__global__ void sort_kernel(const int* __restrict__ roff, int* __restrict__ col, int* __restrict__ eidp) {
    int n = blockIdx.x * 256 + threadIdx.x;
    if (n >= NN) return;
    int a = roff[n], b = roff[n + 1];
    for (int i = a + 1; i < b; i++) {
        int ke = eidp[i], kc = col[i];
        int j = i - 1;
        while (j >= a && eidp[j] > ke) { eidp[j + 1] = eidp[j]; col[j + 1] = col[j]; j--; }
        eidp[j + 1] = ke; col[j + 1] = kc;
    }
}

// ---------------- node transform: XL = x@Wl+bl, XR = x@Wr+br, per-head norms ----------------
template <int IN>
__global__ __launch_bounds__(128) void transform_kernel(
    const float* __restrict__ Xin, const float* __restrict__ Wl, const float* __restrict__ bl,
    const float* __restrict__ Wr, const float* __restrict__ br,
    float* __restrict__ XL, float* __restrict__ XR,
    float* __restrict__ NLn, float* __restrict__ NRn) {
    const int t = threadIdx.x;
    float wl[IN], wr[IN];
#pragma unroll
    for (int k = 0; k < IN; k++) { wl[k] = Wl[k * HCc + t]; wr[k] = Wr[k * HCc + t]; }
    const float blv = bl[t], brv = br[t];
    __shared__ float xrow[IN];
    const int nbeg = blockIdx.x * 16;
    const int nend = (nbeg + 16 < NN) ? (nbeg + 16) : NN;
    for (int n = nbeg; n < nend; n++) {
        __syncthreads();
        if (t < IN) xrow[t] = Xin[n * IN + t];
        __syncthreads();
        float al = blv, ar = brv;
#pragma unroll
        for (int k = 0; k < IN; k++) { float xv = xrow[k]; al = fmaf(xv, wl[k], al); ar = fmaf(xv, wr[k], ar); }
        XL[n * HCc + t] = al;
        XR[n * HCc + t] = ar;
        float sl = al * al, sr = ar * ar;
#pragma unroll
        for (int msk = 1; msk < 32; msk <<= 1) { sl += __shfl_xor(sl, msk); sr += __shfl_xor(sr, msk); }
        if ((t & 31) == 0) { NLn[n * 4 + (t >> 5)] = sqrtf(sl); NRn[n * 4 + (t >> 5)] = sqrtf(sr); }
    }
}

// ---------------- fused per-node GAT layer ----------------
// one wave per destination node; lane owns flat channels (2*lane, 2*lane+1); head = lane>>4
__global__ __launch_bounds__(256) void gat_kernel(
    const float* __restrict__ XL, const float* __restrict__ XR,
    const float* __restrict__ NLn, const float* __restrict__ NRn,
    const int* __restrict__ roff, const int* __restrict__ col, const int* __restrict__ eidp,
    const float* __restrict__ EA, const float* __restrict__ We,
    const float* __restrict__ att, const float* __restrict__ bo,
    float* __restrict__ Hout) {
    const int lane = threadIdx.x & 63;
    const int wv = threadIdx.x >> 6;
    const int i = blockIdx.x * 4 + wv;
    if (i >= NN) return;
    const int base = roff[i];
    const int deg = roff[i + 1] - base;
    const int h = lane >> 4;

    if (deg == 0) {
        if (lane < 16) {
            float2 b2 = reinterpret_cast<const float2*>(bo)[lane];
            float ox = b2.x > 0.f ? b2.x : 0.01f * b2.x;
            float oy = b2.y > 0.f ? b2.y : 0.01f * b2.y;
            reinterpret_cast<float2*>(Hout)[i * 16 + lane] = make_float2(ox, oy);
        }
        return;
    }

    float2 w0 = reinterpret_cast<const float2*>(We)[0 * 64 + lane];
    float2 w1 = reinterpret_cast<const float2*>(We)[1 * 64 + lane];
    float2 w2 = reinterpret_cast<const float2*>(We)[2 * 64 + lane];
    float2 w3 = reinterpret_cast<const float2*>(We)[3 * 64 + lane];
    float2 at = reinterpret_cast<const float2*>(att)[lane];
    float2 xi = reinterpret_cast<const float2*>(XR)[i * 64 + lane];

    // phase 1: mx_h = max over in-edges of ||xl[src]||_h  (order-invariant; norms >= 0)
    float4 mx = make_float4(0.f, 0.f, 0.f, 0.f);
    for (int k = lane; k < deg; k += 64) {
        int j = col[base + k];
        float4 nj = reinterpret_cast<const float4*>(NLn)[j];
        mx.x = fmaxf(mx.x, nj.x); mx.y = fmaxf(mx.y, nj.y);
        mx.z = fmaxf(mx.z, nj.z); mx.w = fmaxf(mx.w, nj.w);
    }
#pragma unroll
    for (int msk = 1; msk < 64; msk <<= 1) {
        mx.x = fmaxf(mx.x, __shfl_xor(mx.x, msk));
        mx.y = fmaxf(mx.y, __shfl_xor(mx.y, msk));
        mx.z = fmaxf(mx.z, __shfl_xor(mx.z, msk));
        mx.w = fmaxf(mx.w, __shfl_xor(mx.w, msk));
    }
    float mxh = (h == 0) ? mx.x : ((h == 1) ? mx.y : ((h == 2) ? mx.z : mx.w));
    float nih = NRn[i * 4 + h];
    float invD = 1.0f / (4.0f * (nih + mxh) + 1e-12f);

    // phase 2: online softmax + weighted aggregation
    float mrun = -__builtin_inff();
    float srun = 0.f;
    float2 acc = make_float2(0.f, 0.f);
    for (int k = 0; k < deg; k++) {
        int j = col[base + k];
        int e = eidp[base + k];
        float2 xj = reinterpret_cast<const float2*>(XL)[j * 64 + lane];
        float4 a4 = reinterpret_cast<const float4*>(EA)[e];
        float efx = a4.x * w0.x; efx = fmaf(a4.y, w1.x, efx); efx = fmaf(a4.z, w2.x, efx); efx = fmaf(a4.w, w3.x, efx);
        float efy = a4.x * w0.y; efy = fmaf(a4.y, w1.y, efy); efy = fmaf(a4.z, w2.y, efy); efy = fmaf(a4.w, w3.y, efy);
        float mmx = xi.x + xj.x + efx; mmx = mmx > 0.f ? mmx : 0.2f * mmx;
        float mmy = xi.y + xj.y + efy; mmy = mmy > 0.f ? mmy : 0.2f * mmy;
        float p = mmx * at.x + mmy * at.y;
#pragma unroll
        for (int msk = 1; msk < 16; msk <<= 1) p += __shfl_xor(p, msk);   // head-group (16 lanes) sum
        float le = p * invD;
        float nm = fmaxf(mrun, le);
        float fct = expf(mrun - nm);
        float z = expf(le - nm);
        srun = srun * fct + z;
        mrun = nm;
        acc.x = acc.x * fct + z * xj.x;
        acc.y = acc.y * fct + z * xj.y;
    }
    float va = acc.x / (srun + 1e-16f);
    float vb = acc.y / (srun + 1e-16f);
    va += __shfl_xor(va, 16); va += __shfl_xor(va, 32);   // sum across 4 heads
    vb += __shfl_xor(vb, 16); vb += __shfl_xor(vb, 32);
    if (lane < 16) {
        float2 b2 = reinterpret_cast<const float2*>(bo)[lane];
        float ox = 0.25f * va + b2.x; ox = ox > 0.f ? ox : 0.01f * ox;
        float oy = 0.25f * vb + b2.y; oy = oy > 0.f ? oy : 0.01f * oy;
        reinterpret_cast<float2*>(Hout)[i * 16 + lane] = make_float2(ox, oy);
    }
}

// ---------------- MLP head ----------------
__global__ __launch_bounds__(256) void mlp_kernel(
    const float* __restrict__ Hin, const float* __restrict__ Wd1, const float* __restrict__ bd1,
    const float* __restrict__ Wd2, const float* __restrict__ bd2, float* __restrict__ out) {
    const int t = threadIdx.x;
    float w1[DHc];
#pragma unroll
    for (int k = 0; k < DHc; k++) w1[k] = Wd1[k * DDd + t];
    float4 w2 = reinterpret_cast<const float4*>(Wd2)[t];
    const float b1 = bd1[t];
    __shared__ float hrow[DHc];
    __shared__ float wpart[4][4];
    const int nbeg = blockIdx.x * 32;
    const int nend = (nbeg + 32 < NN) ? (nbeg + 32) : NN;
    for (int n = nbeg; n < nend; n++) {
        __syncthreads();
        if (t < DHc) hrow[t] = Hin[n * DHc + t];
        __syncthreads();
        float hd = b1;
#pragma unroll
        for (int k = 0; k < DHc; k++) hd = fmaf(hrow[k], w1[k], hd);
        hd = hd > 0.f ? hd : 0.01f * hd;
        float p0 = hd * w2.x, p1 = hd * w2.y, p2 = hd * w2.z, p3 = hd * w2.w;
#pragma unroll
        for (int msk = 1; msk < 64; msk <<= 1) {
            p0 += __shfl_xor(p0, msk); p1 += __shfl_xor(p1, msk);
            p2 += __shfl_xor(p2, msk); p3 += __shfl_xor(p3, msk);
        }
        int wvv = t >> 6;
        if ((t & 63) == 0) { wpart[wvv][0] = p0; wpart[wvv][1] = p1; wpart[wvv][2] = p2; wpart[wvv][3] = p3; }
        __syncthreads();
        if (t < 4) out[n * DOo + t] = wpart[0][t] + wpart[1][t] + wpart[2][t] + wpart[3][t] + bd2[t];
    }
}

extern "C" void kernel_launch(void* const* d_in, const int* in_sizes, int n_in,
                              void* d_out, int out_size, void* d_ws, size_t ws_size,
                              hipStream_t stream) {
    const float* x    = (const float*)d_in[0];
    const void*  eraw = d_in[1];
    const float* ea   = (const float*)d_in[2];
    const float* Wl0  = (const float*)d_in[3];
    const float* bl0  = (const float*)d_in[4];
    const float* Wr0  = (const float*)d_in[5];
    const float* br0  = (const float*)d_in[6];
    const float* We0  = (const float*)d_in[7];
    const float* att0 = (const float*)d_in[8];
    const float* bo0  = (const float*)d_in[9];
    const float* Wl   = (const float*)d_in[10];
    const float* bl   = (const float*)d_in[11];
    const float* Wr   = (const float*)d_in[12];
    const float* br   = (const float*)d_in[13];
    const float* We   = (const float*)d_in[14];
    const float* att  = (const float*)d_in[15];
    const float* bo   = (const float*)d_in[16];
    const float* Wd1  = (const float*)d_in[17];
    const float* bd1  = (const float*)d_in[18];
    const float* Wd2  = (const float*)d_in[19];
    const float* bd2  = (const float*)d_in[20];
    float* out = (float*)d_out;

    char* p = (char*)d_ws;
    auto alloc = [&](size_t bytes) { void* r = (void*)p; p += (bytes + 255) & ~(size_t)255; return r; };
    int*   EI     = (int*)alloc((size_t)2 * EE * 4);
    int*   counts = (int*)alloc((size_t)(NN + 1) * 4);
    int*   roff   = (int*)alloc((size_t)(NN + 1) * 4);
    int*   bsum   = (int*)alloc(256 * 4);
    int*   boff   = (int*)alloc(256 * 4);
    int*   cursor = (int*)alloc((size_t)NN * 4);
    int*   col    = (int*)alloc((size_t)EE * 4);
    int*   eidp   = (int*)alloc((size_t)EE * 4);
    int*   flag   = (int*)alloc(256);
    float* XLb    = (float*)alloc((size_t)NN * HCc * 4);
    float* XRb    = (float*)alloc((size_t)NN * HCc * 4);
    float* NLn    = (float*)alloc((size_t)NN * 4 * 4);
    float* NRn    = (float*)alloc((size_t)NN * 4 * 4);
    float* HA     = (float*)alloc((size_t)NN * DHc * 4);
    float* HB     = (float*)alloc((size_t)NN * DHc * 4);

    (void)hipMemsetAsync(counts, 0, (size_t)(NN + 1) * 4, stream);
    (void)hipMemsetAsync(cursor, 0, (size_t)NN * 4, stream);
    (void)hipMemsetAsync(flag, 0, 4, stream);

    detect_kernel<<<1, 256, 0, stream>>>((const unsigned int*)eraw, 4096, flag);
    convert_kernel<<<(2 * EE + 255) / 256, 256, 0, stream>>>(eraw, flag, EI, 2 * EE);
    count_kernel<<<(EE + 255) / 256, 256, 0, stream>>>(EI, counts);
    const int M = NN + 1;
    const int NBLK = (M + 255) / 256;
    scanA_kernel<<<NBLK, 256, 0, stream>>>(counts, roff, bsum, M);
    scanB_kernel<<<1, 256, 0, stream>>>(bsum, boff, NBLK);
    scanC_kernel<<<NBLK, 256, 0, stream>>>(roff, boff, M);
    fill_kernel<<<(EE + 255) / 256, 256, 0, stream>>>(EI, roff, cursor, col, eidp);
    sort_kernel<<<(NN + 255) / 256, 256, 0, stream>>>(roff, col, eidp);

    const int gT = (NN + 15) / 16;
    const int gG = (NN + 3) / 4;

    // layer 0
    transform_kernel<DFi><<<gT, 128, 0, stream>>>(x, Wl0, bl0, Wr0, br0, XLb, XRb, NLn, NRn);
    gat_kernel<<<gG, 256, 0, stream>>>(XLb, XRb, NLn, NRn, roff, col, eidp, ea, We0, att0, bo0, HA);
    // layer 1
    transform_kernel<DHc><<<gT, 128, 0, stream>>>(HA, Wl, bl, Wr, br, XLb, XRb, NLn, NRn);
    gat_kernel<<<gG, 256, 0, stream>>>(XLb, XRb, NLn, NRn, roff, col, eidp, ea, We, att, bo, HB);
    // layer 2
    transform_kernel<DHc><<<gT, 128, 0, stream>>>(HB, Wl + DHc * HCc, bl + HCc, Wr + DHc * HCc, br + HCc,
                                                  XLb, XRb, NLn, NRn);
    gat_kernel<<<gG, 256, 0, stream>>>(XLb, XRb, NLn, NRn, roff, col, eidp, ea, We + DEe * HCc,
                                       att + Hh * DHc, bo + DHc, HA);
    // MLP head
    mlp_kernel<<<NN / 32 + 1, 256, 0, stream>>>(HA, Wd1, bd1, Wd2, bd2, out);
}

// Round 3
// 551.142 us; speedup vs baseline: 1.3442x; 1.3442x over previous
//
#include <hip/hip_runtime.h>
#include <math.h>

#define NN 50000
#define EE 800000
#define DFi 8
#define DHc 32
#define Hh 4
#define HCc 128
#define DEe 4
#define DDd 256
#define DOo 4

// ---------------- edge-index dtype detect + convert (+count fused) ----------------
__global__ void detect_kernel(const unsigned int* __restrict__ w, int nwords, int* __restrict__ flag) {
    unsigned int acc = 0;
    for (int i = 2 * threadIdx.x + 1; i < nwords; i += 512) acc |= w[i];
    if (acc) atomicOr(flag, 1);
}

__global__ void convert_count_kernel(const void* __restrict__ buf, const int* __restrict__ flag,
                                     int* __restrict__ EI, int* __restrict__ counts) {
    int i = blockIdx.x * 256 + threadIdx.x;
    if (i >= 2 * EE) return;
    int v = (*flag) ? ((const int*)buf)[i] : (int)(((const long long*)buf)[i]);
    EI[i] = v;
    if (i >= EE) atomicAdd(&counts[v], 1);
}

// ---------------- CSR build ----------------
__global__ void scanA_kernel(const int* __restrict__ counts, int* __restrict__ roff,
                             int* __restrict__ bsum, int M) {
    __shared__ int sd[256];
    int t = threadIdx.x;
    int idx = blockIdx.x * 256 + t;
    int v = (idx < M) ? counts[idx] : 0;
    sd[t] = v;
    __syncthreads();
    for (int off = 1; off < 256; off <<= 1) {
        int x = (t >= off) ? sd[t - off] : 0;
        __syncthreads();
        sd[t] += x;
        __syncthreads();
    }
    if (idx < M) roff[idx] = sd[t] - v;      // exclusive
    if (t == 255) bsum[blockIdx.x] = sd[255];
}

__global__ void scanB_kernel(const int* __restrict__ bsum, int* __restrict__ boff, int nb) {
    __shared__ int sd[256];
    int t = threadIdx.x;
    int v = (t < nb) ? bsum[t] : 0;
    sd[t] = v;
    __syncthreads();
    for (int off = 1; off < 256; off <<= 1) {
        int x = (t >= off) ? sd[t - off] : 0;
        __syncthreads();
        sd[t] += x;
        __syncthreads();
    }
    boff[t] = sd[t] - v;                     // exclusive
}

__global__ void scanC_kernel(int* __restrict__ roff, const int* __restrict__ boff, int M) {
    int idx = blockIdx.x * 256 + threadIdx.x;
    if (idx < M) roff[idx] += boff[idx >> 8];
}

__global__ void fill_kernel(const int* __restrict__ EI, const int* __restrict__ roff,
                            int* __restrict__ cursor, long long* __restrict__ ce) {
    int e = blockIdx.x * 256 + threadIdx.x;
    if (e >= EE) return;
    int d = EI[EE + e];
    int s = EI[e];
    int pos = atomicAdd(&cursor[d], 1);
    ce[roff[d] + pos] = ((long long)e << 32) | (unsigned int)s;
}

// deterministic order within each segment: insertion sort by packed key (eid in high bits)
__global__ void sort_kernel(const int* __restrict__ roff, long long* __restrict__ ce) {
    int n = blockIdx.x * 256 + threadIdx.x;
    if (n >= NN) return;
    int a = roff[n], b = roff[n + 1];
    for (int i = a + 1; i < b; i++) {
        long long key = ce[i];
        int j = i - 1;
        while (j >= a && ce[j] > key) { ce[j + 1] = ce[j]; j--; }
        ce[j + 1] = key;
    }
}

// ---------------- node transform: XL = x@Wl+bl, XR = x@Wr+br, per-head norms ----------------
template <int IN>
__global__ __launch_bounds__(128) void transform_kernel(
    const float* __restrict__ Xin, const float* __restrict__ Wl, const float* __restrict__ bl,
    const float* __restrict__ Wr, const float* __restrict__ br,
    float* __restrict__ XL, float* __restrict__ XR,
    float* __restrict__ NLn, float* __restrict__ NRn) {
    const int t = threadIdx.x;
    float wl[IN], wr[IN];
#pragma unroll
    for (int k = 0; k < IN; k++) { wl[k] = Wl[k * HCc + t]; wr[k] = Wr[k * HCc + t]; }
    const float blv = bl[t], brv = br[t];
    __shared__ float xrow[IN];
    const int nbeg = blockIdx.x * 16;
    const int nend = (nbeg + 16 < NN) ? (nbeg + 16) : NN;
    for (int n = nbeg; n < nend; n++) {
        __syncthreads();
        if (t < IN) xrow[t] = Xin[n * IN + t];
        __syncthreads();
        float al = blv, ar = brv;
#pragma unroll
        for (int k = 0; k < IN; k++) { float xv = xrow[k]; al = fmaf(xv, wl[k], al); ar = fmaf(xv, wr[k], ar); }
        XL[n * HCc + t] = al;
        XR[n * HCc + t] = ar;
        float sl = al * al, sr = ar * ar;
#pragma unroll
        for (int msk = 1; msk < 32; msk <<= 1) { sl += __shfl_xor(sl, msk); sr += __shfl_xor(sr, msk); }
        if ((t & 31) == 0) { NLn[n * 4 + (t >> 5)] = sqrtf(sl); NRn[n * 4 + (t >> 5)] = sqrtf(sr); }
    }
}

// ---------------- fused per-node GAT layer ----------------
// one wave per destination node; lane owns float4 of channels (4c..4c+3), c=lane&31;
// two edge-groups (lane>>5) process even/odd CSR slots with private online softmax, merged at end.
__global__ __launch_bounds__(256) void gat_kernel(
    const float* __restrict__ XL, const float* __restrict__ XR,
    const float* __restrict__ NLn, const float* __restrict__ NRn,
    const int* __restrict__ roff, const long long* __restrict__ ce,
    const float* __restrict__ EA, const float* __restrict__ We,
    const float* __restrict__ att, const float* __restrict__ bo,
    float* __restrict__ Hout) {
    const int lane = threadIdx.x & 63;
    const int wv = threadIdx.x >> 6;
    const int i = blockIdx.x * 4 + wv;
    if (i >= NN) return;
    const int base = roff[i];
    const int deg = roff[i + 1] - base;
    const int c = lane & 31;
    const int g = lane >> 5;
    const int h = c >> 3;

    const float4* XL4 = reinterpret_cast<const float4*>(XL);
    const float4* XR4 = reinterpret_cast<const float4*>(XR);
    const float4* NL4 = reinterpret_cast<const float4*>(NLn);
    const float4* EA4 = reinterpret_cast<const float4*>(EA);
    const float4* We4 = reinterpret_cast<const float4*>(We);
    const float4* at4 = reinterpret_cast<const float4*>(att);
    const float4* bo4 = reinterpret_cast<const float4*>(bo);
    float4* Ho4 = reinterpret_cast<float4*>(Hout);

    if (deg == 0) {
        if (lane < 8) {
            float4 b = bo4[lane];
            float4 r;
            r.x = b.x > 0.f ? b.x : 0.01f * b.x;
            r.y = b.y > 0.f ? b.y : 0.01f * b.y;
            r.z = b.z > 0.f ? b.z : 0.01f * b.z;
            r.w = b.w > 0.f ? b.w : 0.01f * b.w;
            Ho4[i * 8 + lane] = r;
        }
        return;
    }

    // phase 1: per-lane edge regs (first 64 edges) + Lipschitz max of source norms
    int jreg = 0, ereg = 0;
    float4 mx = make_float4(0.f, 0.f, 0.f, 0.f);
    if (lane < deg) {
        long long v = ce[base + lane];
        jreg = (int)(v & 0xffffffffLL);
        ereg = (int)(v >> 32);
        mx = NL4[jreg];
    }
    for (int k = lane + 64; k < deg; k += 64) {
        long long v = ce[base + k];
        int j2 = (int)(v & 0xffffffffLL);
        float4 nj = NL4[j2];
        mx.x = fmaxf(mx.x, nj.x); mx.y = fmaxf(mx.y, nj.y);
        mx.z = fmaxf(mx.z, nj.z); mx.w = fmaxf(mx.w, nj.w);
    }
#pragma unroll
    for (int msk = 1; msk < 64; msk <<= 1) {
        mx.x = fmaxf(mx.x, __shfl_xor(mx.x, msk));
        mx.y = fmaxf(mx.y, __shfl_xor(mx.y, msk));
        mx.z = fmaxf(mx.z, __shfl_xor(mx.z, msk));
        mx.w = fmaxf(mx.w, __shfl_xor(mx.w, msk));
    }
    float mxh = (h == 0) ? mx.x : (h == 1) ? mx.y : (h == 2) ? mx.z : mx.w;
    float nih = NRn[i * 4 + h];
    float invD = 1.0f / (4.0f * (nih + mxh) + 1e-12f);

    float4 w0 = We4[c], w1 = We4[32 + c], w2 = We4[64 + c], w3 = We4[96 + c];
    float4 at = at4[c];
    float4 xi = XR4[i * 32 + c];

    float mrun = -__builtin_inff();
    float srun = 0.f;
    float4 acc = make_float4(0.f, 0.f, 0.f, 0.f);

#define EDGE_BODY(XJ, A4)                                                       \
    {                                                                           \
        float efx = (A4).x * w0.x; efx = fmaf((A4).y, w1.x, efx);               \
        efx = fmaf((A4).z, w2.x, efx); efx = fmaf((A4).w, w3.x, efx);           \
        float efy = (A4).x * w0.y; efy = fmaf((A4).y, w1.y, efy);               \
        efy = fmaf((A4).z, w2.y, efy); efy = fmaf((A4).w, w3.y, efy);           \
        float efz = (A4).x * w0.z; efz = fmaf((A4).y, w1.z, efz);               \
        efz = fmaf((A4).z, w2.z, efz); efz = fmaf((A4).w, w3.z, efz);           \
        float efw = (A4).x * w0.w; efw = fmaf((A4).y, w1.w, efw);               \
        efw = fmaf((A4).z, w2.w, efw); efw = fmaf((A4).w, w3.w, efw);           \
        float sx = xi.x + (XJ).x + efx; sx = sx > 0.f ? sx : 0.2f * sx;         \
        float sy = xi.y + (XJ).y + efy; sy = sy > 0.f ? sy : 0.2f * sy;         \
        float sz = xi.z + (XJ).z + efz; sz = sz > 0.f ? sz : 0.2f * sz;         \
        float sw = xi.w + (XJ).w + efw; sw = sw > 0.f ? sw : 0.2f * sw;         \
        float p = sx * at.x; p = fmaf(sy, at.y, p);                             \
        p = fmaf(sz, at.z, p); p = fmaf(sw, at.w, p);                           \
        p += __shfl_xor(p, 1); p += __shfl_xor(p, 2); p += __shfl_xor(p, 4);    \
        float le = p * invD;                                                    \
        float nm = fmaxf(mrun, le);                                             \
        float fct = __expf(mrun - nm);                                          \
        float z = __expf(le - nm);                                              \
        srun = srun * fct + z;                                                  \
        mrun = nm;                                                              \
        acc.x = fmaf(z, (XJ).x, acc.x * fct);                                   \
        acc.y = fmaf(z, (XJ).y, acc.y * fct);                                   \
        acc.z = fmaf(z, (XJ).z, acc.z * fct);                                   \
        acc.w = fmaf(z, (XJ).w, acc.w * fct);                                   \
    }

    if (deg <= 64) {
        int kk = g;
        if (kk < deg) {
            int jc = __shfl(jreg, kk);
            int ec = __shfl(ereg, kk);
            float4 xj = XL4[jc * 32 + c];
            float4 a4 = EA4[ec];
            while (true) {
                int kn = kk + 2;
                float4 xjn, a4n;
                if (kn < deg) {
                    int jn = __shfl(jreg, kn);
                    int en = __shfl(ereg, kn);
                    xjn = XL4[jn * 32 + c];
                    a4n = EA4[en];
                } else {
                    xjn = make_float4(0.f, 0.f, 0.f, 0.f);
                    a4n = make_float4(0.f, 0.f, 0.f, 0.f);
                }
                EDGE_BODY(xj, a4);
                if (kn >= deg) break;
                xj = xjn; a4 = a4n; kk = kn;
            }
        }
    } else {
        for (int kk = g; kk < deg; kk += 2) {
            long long v = ce[base + kk];
            int jc = (int)(v & 0xffffffffLL);
            int ec = (int)(v >> 32);
            float4 xj = XL4[jc * 32 + c];
            float4 a4 = EA4[ec];
            EDGE_BODY(xj, a4);
        }
    }
#undef EDGE_BODY

    // merge the two groups' online-softmax states (flash-style)
    float mo = __shfl_xor(mrun, 32);
    float so = __shfl_xor(srun, 32);
    float4 ao;
    ao.x = __shfl_xor(acc.x, 32);
    ao.y = __shfl_xor(acc.y, 32);
    ao.z = __shfl_xor(acc.z, 32);
    ao.w = __shfl_xor(acc.w, 32);
    float mm = fmaxf(mrun, mo);
    float fs = __expf(mrun - mm);
    float fo = __expf(mo - mm);
    float s = srun * fs + so * fo;
    float inv = 1.0f / (s + 1e-16f);
    float4 am;
    am.x = (acc.x * fs + ao.x * fo) * inv;
    am.y = (acc.y * fs + ao.y * fo) * inv;
    am.z = (acc.z * fs + ao.z * fo) * inv;
    am.w = (acc.w * fs + ao.w * fo) * inv;

    // head mean: sum heads via xor 8 and 16 within each 32-lane half
    am.x += __shfl_xor(am.x, 8); am.x += __shfl_xor(am.x, 16);
    am.y += __shfl_xor(am.y, 8); am.y += __shfl_xor(am.y, 16);
    am.z += __shfl_xor(am.z, 8); am.z += __shfl_xor(am.z, 16);
    am.w += __shfl_xor(am.w, 8); am.w += __shfl_xor(am.w, 16);

    if (lane < 8) {
        float4 b = bo4[lane];
        float4 r;
        r.x = fmaf(0.25f, am.x, b.x); r.x = r.x > 0.f ? r.x : 0.01f * r.x;
        r.y = fmaf(0.25f, am.y, b.y); r.y = r.y > 0.f ? r.y : 0.01f * r.y;
        r.z = fmaf(0.25f, am.z, b.z); r.z = r.z > 0.f ? r.z : 0.01f * r.z;
        r.w = fmaf(0.25f, am.w, b.w); r.w = r.w > 0.f ? r.w : 0.01f * r.w;
        Ho4[i * 8 + lane] = r;
    }
}

// ---------------- MLP head ----------------
__global__ __launch_bounds__(256) void mlp_kernel(
    const float* __restrict__ Hin, const float* __restrict__ Wd1, const float* __restrict__ bd1,
    const float* __restrict__ Wd2, const float* __restrict__ bd2, float* __restrict__ out) {
    const int t = threadIdx.x;
    float w1[DHc];
#pragma unroll
    for (int k = 0; k < DHc; k++) w1[k] = Wd1[k * DDd + t];
    float4 w2 = reinterpret_cast<const float4*>(Wd2)[t];
    const float b1 = bd1[t];
    __shared__ float hrow[DHc];
    __shared__ float wpart[4][4];
    const int nbeg = blockIdx.x * 32;
    const int nend = (nbeg + 32 < NN) ? (nbeg + 32) : NN;
    for (int n = nbeg; n < nend; n++) {
        __syncthreads();
        if (t < DHc) hrow[t] = Hin[n * DHc + t];
        __syncthreads();
        float hd = b1;
#pragma unroll
        for (int k = 0; k < DHc; k++) hd = fmaf(hrow[k], w1[k], hd);
        hd = hd > 0.f ? hd : 0.01f * hd;
        float p0 = hd * w2.x, p1 = hd * w2.y, p2 = hd * w2.z, p3 = hd * w2.w;
#pragma unroll
        for (int msk = 1; msk < 64; msk <<= 1) {
            p0 += __shfl_xor(p0, msk); p1 += __shfl_xor(p1, msk);
            p2 += __shfl_xor(p2, msk); p3 += __shfl_xor(p3, msk);
        }
        int wvv = t >> 6;
        if ((t & 63) == 0) { wpart[wvv][0] = p0; wpart[wvv][1] = p1; wpart[wvv][2] = p2; wpart[wvv][3] = p3; }
        __syncthreads();
        if (t < 4) out[n * DOo + t] = wpart[0][t] + wpart[1][t] + wpart[2][t] + wpart[3][t] + bd2[t];
    }
}

extern "C" void kernel_launch(void* const* d_in, const int* in_sizes, int n_in,
                              void* d_out, int out_size, void* d_ws, size_t ws_size,
                              hipStream_t stream) {
    const float* x    = (const float*)d_in[0];
    const void*  eraw = d_in[1];
    const float* ea   = (const float*)d_in[2];
    const float* Wl0  = (const float*)d_in[3];
    const float* bl0  = (const float*)d_in[4];
    const float* Wr0  = (const float*)d_in[5];
    const float* br0  = (const float*)d_in[6];
    const float* We0  = (const float*)d_in[7];
    const float* att0 = (const float*)d_in[8];
    const float* bo0  = (const float*)d_in[9];
    const float* Wl   = (const float*)d_in[10];
    const float* bl   = (const float*)d_in[11];
    const float* Wr   = (const float*)d_in[12];
    const float* br   = (const float*)d_in[13];
    const float* We   = (const float*)d_in[14];
    const float* att  = (const float*)d_in[15];
    const float* bo   = (const float*)d_in[16];
    const float* Wd1  = (const float*)d_in[17];
    const float* bd1  = (const float*)d_in[18];
    const float* Wd2  = (const float*)d_in[19];
    const float* bd2  = (const float*)d_in[20];
    float* out = (float*)d_out;

    char* p = (char*)d_ws;
    auto alloc = [&](size_t bytes) { void* r = (void*)p; p += (bytes + 255) & ~(size_t)255; return r; };
    int*       EI     = (int*)alloc((size_t)2 * EE * 4);
    int*       counts = (int*)alloc((size_t)(NN + 1) * 4);
    int*       roff   = (int*)alloc((size_t)(NN + 1) * 4);
    int*       bsum   = (int*)alloc(256 * 4);
    int*       boff   = (int*)alloc(256 * 4);
    int*       cursor = (int*)alloc((size_t)NN * 4);
    long long* ce     = (long long*)alloc((size_t)EE * 8);
    int*       flag   = (int*)alloc(256);
    float*     XLb    = (float*)alloc((size_t)NN * HCc * 4);
    float*     XRb    = (float*)alloc((size_t)NN * HCc * 4);
    float*     NLn    = (float*)alloc((size_t)NN * 4 * 4);
    float*     NRn    = (float*)alloc((size_t)NN * 4 * 4);
    float*     HA     = (float*)alloc((size_t)NN * DHc * 4);
    float*     HB     = (float*)alloc((size_t)NN * DHc * 4);

    (void)hipMemsetAsync(counts, 0, (size_t)(NN + 1) * 4, stream);
    (void)hipMemsetAsync(cursor, 0, (size_t)NN * 4, stream);
    (void)hipMemsetAsync(flag, 0, 4, stream);

    detect_kernel<<<1, 256, 0, stream>>>((const unsigned int*)eraw, 8192, flag);
    convert_count_kernel<<<(2 * EE + 255) / 256, 256, 0, stream>>>(eraw, flag, EI, counts);
    const int M = NN + 1;
    const int NBLK = (M + 255) / 256;
    scanA_kernel<<<NBLK, 256, 0, stream>>>(counts, roff, bsum, M);
    scanB_kernel<<<1, 256, 0, stream>>>(bsum, boff, NBLK);
    scanC_kernel<<<NBLK, 256, 0, stream>>>(roff, boff, M);
    fill_kernel<<<(EE + 255) / 256, 256, 0, stream>>>(EI, roff, cursor, ce);
    sort_kernel<<<(NN + 255) / 256, 256, 0, stream>>>(roff, ce);

    const int gT = (NN + 15) / 16;
    const int gG = (NN + 3) / 4;

    // layer 0
    transform_kernel<DFi><<<gT, 128, 0, stream>>>(x, Wl0, bl0, Wr0, br0, XLb, XRb, NLn, NRn);
    gat_kernel<<<gG, 256, 0, stream>>>(XLb, XRb, NLn, NRn, roff, ce, ea, We0, att0, bo0, HA);
    // layer 1
    transform_kernel<DHc><<<gT, 128, 0, stream>>>(HA, Wl, bl, Wr, br, XLb, XRb, NLn, NRn);
    gat_kernel<<<gG, 256, 0, stream>>>(XLb, XRb, NLn, NRn, roff, ce, ea, We, att, bo, HB);
    // layer 2
    transform_kernel<DHc><<<gT, 128, 0, stream>>>(HB, Wl + DHc * HCc, bl + HCc, Wr + DHc * HCc, br + HCc,
                                                  XLb, XRb, NLn, NRn);
    gat_kernel<<<gG, 256, 0, stream>>>(XLb, XRb, NLn, NRn, roff, ce, ea, We + DEe * HCc,
                                       att + Hh * DHc, bo + DHc, HA);
    // MLP head
    mlp_kernel<<<NN / 32 + 1, 256, 0, stream>>>(HA, Wd1, bd1, Wd2, bd2, out);
}

// Round 4
// 529.538 us; speedup vs baseline: 1.3990x; 1.0408x over previous
//
#include <hip/hip_runtime.h>
#include <math.h>

#define NN 50000
#define EE 800000
#define DFi 8
#define DHc 32
#define Hh 4
#define HCc 128
#define DEe 4
#define DDd 256
#define DOo 4

// ---------------- edge-index dtype detect + convert (+count fused) ----------------
__global__ void detect_kernel(const unsigned int* __restrict__ w, int nwords, int* __restrict__ flag) {
    unsigned int acc = 0;
    for (int i = 2 * threadIdx.x + 1; i < nwords; i += 512) acc |= w[i];
    if (acc) atomicOr(flag, 1);
}

__global__ void convert_count_kernel(const void* __restrict__ buf, const int* __restrict__ flag,
                                     int* __restrict__ EI, int* __restrict__ counts) {
    int i = blockIdx.x * 256 + threadIdx.x;
    if (i >= 2 * EE) return;
    int v = (*flag) ? ((const int*)buf)[i] : (int)(((const long long*)buf)[i]);
    EI[i] = v;
    if (i >= EE) atomicAdd(&counts[v], 1);
}

// ---------------- CSR build ----------------
__global__ void scanA_kernel(const int* __restrict__ counts, int* __restrict__ roff,
                             int* __restrict__ bsum, int M) {
    __shared__ int sd[256];
    int t = threadIdx.x;
    int idx = blockIdx.x * 256 + t;
    int v = (idx < M) ? counts[idx] : 0;
    sd[t] = v;
    __syncthreads();
    for (int off = 1; off < 256; off <<= 1) {
        int x = (t >= off) ? sd[t - off] : 0;
        __syncthreads();
        sd[t] += x;
        __syncthreads();
    }
    if (idx < M) roff[idx] = sd[t] - v;      // exclusive
    if (t == 255) bsum[blockIdx.x] = sd[255];
}

__global__ void scanB_kernel(const int* __restrict__ bsum, int* __restrict__ boff, int nb) {
    __shared__ int sd[256];
    int t = threadIdx.x;
    int v = (t < nb) ? bsum[t] : 0;
    sd[t] = v;
    __syncthreads();
    for (int off = 1; off < 256; off <<= 1) {
        int x = (t >= off) ? sd[t - off] : 0;
        __syncthreads();
        sd[t] += x;
        __syncthreads();
    }
    boff[t] = sd[t] - v;                     // exclusive
}

__global__ void scanC_kernel(int* __restrict__ roff, const int* __restrict__ boff, int M) {
    int idx = blockIdx.x * 256 + threadIdx.x;
    if (idx < M) roff[idx] += boff[idx >> 8];
}

__global__ void fill_kernel(const int* __restrict__ EI, const int* __restrict__ roff,
                            int* __restrict__ cursor, long long* __restrict__ ce) {
    int e = blockIdx.x * 256 + threadIdx.x;
    if (e >= EE) return;
    int d = EI[EE + e];
    int s = EI[e];
    int pos = atomicAdd(&cursor[d], 1);
    ce[roff[d] + pos] = ((long long)e << 32) | (unsigned int)s;
}

// deterministic order within each segment: insertion sort by packed key (eid in high bits)
__global__ void sort_kernel(const int* __restrict__ roff, long long* __restrict__ ce) {
    int n = blockIdx.x * 256 + threadIdx.x;
    if (n >= NN) return;
    int a = roff[n], b = roff[n + 1];
    for (int i = a + 1; i < b; i++) {
        long long key = ce[i];
        int j = i - 1;
        while (j >= a && ce[j] > key) { ce[j + 1] = ce[j]; j--; }
        ce[j + 1] = key;
    }
}

// ---------------- node transform: XL = x@Wl+bl, XR = x@Wr+br, per-head norms ----------------
template <int IN>
__global__ __launch_bounds__(128) void transform_kernel(
    const float* __restrict__ Xin, const float* __restrict__ Wl, const float* __restrict__ bl,
    const float* __restrict__ Wr, const float* __restrict__ br,
    float* __restrict__ XL, float* __restrict__ XR,
    float* __restrict__ NLn, float* __restrict__ NRn) {
    const int t = threadIdx.x;
    float wl[IN], wr[IN];
#pragma unroll
    for (int k = 0; k < IN; k++) { wl[k] = Wl[k * HCc + t]; wr[k] = Wr[k * HCc + t]; }
    const float blv = bl[t], brv = br[t];
    __shared__ float xrow[IN];
    const int nbeg = blockIdx.x * 16;
    const int nend = (nbeg + 16 < NN) ? (nbeg + 16) : NN;
    for (int n = nbeg; n < nend; n++) {
        __syncthreads();
        if (t < IN) xrow[t] = Xin[n * IN + t];
        __syncthreads();
        float al = blv, ar = brv;
#pragma unroll
        for (int k = 0; k < IN; k++) { float xv = xrow[k]; al = fmaf(xv, wl[k], al); ar = fmaf(xv, wr[k], ar); }
        XL[n * HCc + t] = al;
        XR[n * HCc + t] = ar;
        float sl = al * al, sr = ar * ar;
#pragma unroll
        for (int msk = 1; msk < 32; msk <<= 1) { sl += __shfl_xor(sl, msk); sr += __shfl_xor(sr, msk); }
        if ((t & 31) == 0) { NLn[n * 4 + (t >> 5)] = sqrtf(sl); NRn[n * 4 + (t >> 5)] = sqrtf(sr); }
    }
}

// ---------------- fused per-node GAT layer ----------------
// one wave per destination node; lane = (g, c): g = lane>>4 edge-group, c = lane&15 owns
// flat channels 8c..8c+7 (head = c>>2). 4 edges processed per wave-step.
// softmax without max-shift: logits are structurally bounded (|le| small), clamped at 60.
__global__ __launch_bounds__(256) void gat_kernel(
    const float* __restrict__ XL, const float* __restrict__ XR,
    const float* __restrict__ NLn, const float* __restrict__ NRn,
    const int* __restrict__ roff, const long long* __restrict__ ce,
    const float* __restrict__ EA, const float* __restrict__ We,
    const float* __restrict__ att, const float* __restrict__ bo,
    float* __restrict__ Hout) {
    const int lane = threadIdx.x & 63;
    const int wv = threadIdx.x >> 6;
    const int i = blockIdx.x * 4 + wv;
    if (i >= NN) return;
    const int base = roff[i];
    const int deg = roff[i + 1] - base;
    const int c = lane & 15;
    const int g = lane >> 4;
    const int h = c >> 2;

    const float4* XL4 = reinterpret_cast<const float4*>(XL);
    const float4* XR4 = reinterpret_cast<const float4*>(XR);
    const float4* NL4 = reinterpret_cast<const float4*>(NLn);
    const float4* EA4 = reinterpret_cast<const float4*>(EA);
    const float4* We4 = reinterpret_cast<const float4*>(We);
    const float4* at4 = reinterpret_cast<const float4*>(att);
    const float4* bo4 = reinterpret_cast<const float4*>(bo);
    float4* Ho4 = reinterpret_cast<float4*>(Hout);

    if (deg == 0) {
        if (lane < 8) {
            float4 b = bo4[lane];
            float4 r;
            r.x = b.x > 0.f ? b.x : 0.01f * b.x;
            r.y = b.y > 0.f ? b.y : 0.01f * b.y;
            r.z = b.z > 0.f ? b.z : 0.01f * b.z;
            r.w = b.w > 0.f ? b.w : 0.01f * b.w;
            Ho4[i * 8 + lane] = r;
        }
        return;
    }

    // phase 1: Lipschitz max of source norms over in-edges (order-invariant; norms >= 0)
    float4 mx = make_float4(0.f, 0.f, 0.f, 0.f);
    for (int k = lane; k < deg; k += 64) {
        long long v = ce[base + k];
        int j = (int)(v & 0xffffffffLL);
        float4 nj = NL4[j];
        mx.x = fmaxf(mx.x, nj.x); mx.y = fmaxf(mx.y, nj.y);
        mx.z = fmaxf(mx.z, nj.z); mx.w = fmaxf(mx.w, nj.w);
    }
#pragma unroll
    for (int msk = 1; msk < 64; msk <<= 1) {
        mx.x = fmaxf(mx.x, __shfl_xor(mx.x, msk));
        mx.y = fmaxf(mx.y, __shfl_xor(mx.y, msk));
        mx.z = fmaxf(mx.z, __shfl_xor(mx.z, msk));
        mx.w = fmaxf(mx.w, __shfl_xor(mx.w, msk));
    }
    float mxh = (h == 0) ? mx.x : (h == 1) ? mx.y : (h == 2) ? mx.z : mx.w;
    float invD = 1.0f / (4.0f * (NRn[i * 4 + h] + mxh) + 1e-12f);

    // per-lane constants: We columns (8 channels), att, xi
    float4 w0l = We4[2 * c],      w0h = We4[2 * c + 1];
    float4 w1l = We4[32 + 2 * c], w1h = We4[32 + 2 * c + 1];
    float4 w2l = We4[64 + 2 * c], w2h = We4[64 + 2 * c + 1];
    float4 w3l = We4[96 + 2 * c], w3h = We4[96 + 2 * c + 1];
    float4 atl = at4[2 * c],      ath = at4[2 * c + 1];
    float4 xil = XR4[i * 32 + 2 * c], xih = XR4[i * 32 + 2 * c + 1];

    float srun = 0.f;
    float4 accl = make_float4(0.f, 0.f, 0.f, 0.f);
    float4 acch = make_float4(0.f, 0.f, 0.f, 0.f);

    const int nsteps = (deg + 3) >> 2;
    int kk = g;
    // prologue: step 0 data + step 1 ce in flight
    long long v0 = ce[base + (kk < deg ? kk : 0)];
    int jc = (int)(v0 & 0xffffffffLL);
    int ec = (int)(v0 >> 32);
    float4 xjlA = XL4[jc * 32 + 2 * c];
    float4 xjhA = XL4[jc * 32 + 2 * c + 1];
    float4 a4A  = EA4[ec];
    int k1 = kk + 4;
    long long vN = ce[base + (k1 < deg ? k1 : 0)];

    for (int s = 0; s < nsteps; ++s) {
        const bool more = (s + 1 < nsteps);
        float4 xjlB, xjhB, a4B;
        if (more) {
            int jn = (int)(vN & 0xffffffffLL);
            int en = (int)(vN >> 32);
            xjlB = XL4[jn * 32 + 2 * c];
            xjhB = XL4[jn * 32 + 2 * c + 1];
            a4B  = EA4[en];
            int k2 = kk + 8;
            vN = ce[base + (k2 < deg ? k2 : 0)];
        }
        // body on current
        float e0 = a4A.x * w0l.x; e0 = fmaf(a4A.y, w1l.x, e0); e0 = fmaf(a4A.z, w2l.x, e0); e0 = fmaf(a4A.w, w3l.x, e0);
        float e1 = a4A.x * w0l.y; e1 = fmaf(a4A.y, w1l.y, e1); e1 = fmaf(a4A.z, w2l.y, e1); e1 = fmaf(a4A.w, w3l.y, e1);
        float e2 = a4A.x * w0l.z; e2 = fmaf(a4A.y, w1l.z, e2); e2 = fmaf(a4A.z, w2l.z, e2); e2 = fmaf(a4A.w, w3l.z, e2);
        float e3 = a4A.x * w0l.w; e3 = fmaf(a4A.y, w1l.w, e3); e3 = fmaf(a4A.z, w2l.w, e3); e3 = fmaf(a4A.w, w3l.w, e3);
        float e4 = a4A.x * w0h.x; e4 = fmaf(a4A.y, w1h.x, e4); e4 = fmaf(a4A.z, w2h.x, e4); e4 = fmaf(a4A.w, w3h.x, e4);
        float e5 = a4A.x * w0h.y; e5 = fmaf(a4A.y, w1h.y, e5); e5 = fmaf(a4A.z, w2h.y, e5); e5 = fmaf(a4A.w, w3h.y, e5);
        float e6 = a4A.x * w0h.z; e6 = fmaf(a4A.y, w1h.z, e6); e6 = fmaf(a4A.z, w2h.z, e6); e6 = fmaf(a4A.w, w3h.z, e6);
        float e7 = a4A.x * w0h.w; e7 = fmaf(a4A.y, w1h.w, e7); e7 = fmaf(a4A.z, w2h.w, e7); e7 = fmaf(a4A.w, w3h.w, e7);
        float s0 = xil.x + xjlA.x + e0; s0 = s0 > 0.f ? s0 : 0.2f * s0;
        float s1 = xil.y + xjlA.y + e1; s1 = s1 > 0.f ? s1 : 0.2f * s1;
        float s2 = xil.z + xjlA.z + e2; s2 = s2 > 0.f ? s2 : 0.2f * s2;
        float s3 = xil.w + xjlA.w + e3; s3 = s3 > 0.f ? s3 : 0.2f * s3;
        float s4 = xih.x + xjhA.x + e4; s4 = s4 > 0.f ? s4 : 0.2f * s4;
        float s5 = xih.y + xjhA.y + e5; s5 = s5 > 0.f ? s5 : 0.2f * s5;
        float s6 = xih.z + xjhA.z + e6; s6 = s6 > 0.f ? s6 : 0.2f * s6;
        float s7 = xih.w + xjhA.w + e7; s7 = s7 > 0.f ? s7 : 0.2f * s7;
        float pp = s0 * atl.x; pp = fmaf(s1, atl.y, pp); pp = fmaf(s2, atl.z, pp); pp = fmaf(s3, atl.w, pp);
        pp = fmaf(s4, ath.x, pp); pp = fmaf(s5, ath.y, pp); pp = fmaf(s6, ath.z, pp); pp = fmaf(s7, ath.w, pp);
        pp += __shfl_xor(pp, 1);
        pp += __shfl_xor(pp, 2);
        float z = __expf(fminf(pp * invD, 60.f));
        z = (kk < deg) ? z : 0.f;
        srun += z;
        accl.x = fmaf(z, xjlA.x, accl.x);
        accl.y = fmaf(z, xjlA.y, accl.y);
        accl.z = fmaf(z, xjlA.z, accl.z);
        accl.w = fmaf(z, xjlA.w, accl.w);
        acch.x = fmaf(z, xjhA.x, acch.x);
        acch.y = fmaf(z, xjhA.y, acch.y);
        acch.z = fmaf(z, xjhA.z, acch.z);
        acch.w = fmaf(z, xjhA.w, acch.w);
        if (more) { xjlA = xjlB; xjhA = xjhB; a4A = a4B; }
        kk += 4;
    }

    // merge the 4 edge-groups (pure sums — no max-shift needed)
    srun += __shfl_xor(srun, 16); srun += __shfl_xor(srun, 32);
    accl.x += __shfl_xor(accl.x, 16); accl.x += __shfl_xor(accl.x, 32);
    accl.y += __shfl_xor(accl.y, 16); accl.y += __shfl_xor(accl.y, 32);
    accl.z += __shfl_xor(accl.z, 16); accl.z += __shfl_xor(accl.z, 32);
    accl.w += __shfl_xor(accl.w, 16); accl.w += __shfl_xor(accl.w, 32);
    acch.x += __shfl_xor(acch.x, 16); acch.x += __shfl_xor(acch.x, 32);
    acch.y += __shfl_xor(acch.y, 16); acch.y += __shfl_xor(acch.y, 32);
    acch.z += __shfl_xor(acch.z, 16); acch.z += __shfl_xor(acch.z, 32);
    acch.w += __shfl_xor(acch.w, 16); acch.w += __shfl_xor(acch.w, 32);
    float inv = 1.0f / (srun + 1e-16f);
    float a0 = accl.x * inv, a1 = accl.y * inv, a2 = accl.z * inv, a3 = accl.w * inv;
    float a4_ = acch.x * inv, a5 = acch.y * inv, a6 = acch.z * inv, a7 = acch.w * inv;
    // head mean: sum over c bits 2,3 (heads), result at lanes c<4
    a0 += __shfl_xor(a0, 4); a0 += __shfl_xor(a0, 8);
    a1 += __shfl_xor(a1, 4); a1 += __shfl_xor(a1, 8);
    a2 += __shfl_xor(a2, 4); a2 += __shfl_xor(a2, 8);
    a3 += __shfl_xor(a3, 4); a3 += __shfl_xor(a3, 8);
    a4_ += __shfl_xor(a4_, 4); a4_ += __shfl_xor(a4_, 8);
    a5 += __shfl_xor(a5, 4); a5 += __shfl_xor(a5, 8);
    a6 += __shfl_xor(a6, 4); a6 += __shfl_xor(a6, 8);
    a7 += __shfl_xor(a7, 4); a7 += __shfl_xor(a7, 8);

    if (lane < 4) {
        float4 bl_ = bo4[2 * lane], bh_ = bo4[2 * lane + 1];
        float4 rl, rh;
        rl.x = fmaf(0.25f, a0, bl_.x); rl.x = rl.x > 0.f ? rl.x : 0.01f * rl.x;
        rl.y = fmaf(0.25f, a1, bl_.y); rl.y = rl.y > 0.f ? rl.y : 0.01f * rl.y;
        rl.z = fmaf(0.25f, a2, bl_.z); rl.z = rl.z > 0.f ? rl.z : 0.01f * rl.z;
        rl.w = fmaf(0.25f, a3, bl_.w); rl.w = rl.w > 0.f ? rl.w : 0.01f * rl.w;
        rh.x = fmaf(0.25f, a4_, bh_.x); rh.x = rh.x > 0.f ? rh.x : 0.01f * rh.x;
        rh.y = fmaf(0.25f, a5, bh_.y); rh.y = rh.y > 0.f ? rh.y : 0.01f * rh.y;
        rh.z = fmaf(0.25f, a6, bh_.z); rh.z = rh.z > 0.f ? rh.z : 0.01f * rh.z;
        rh.w = fmaf(0.25f, a7, bh_.w); rh.w = rh.w > 0.f ? rh.w : 0.01f * rh.w;
        Ho4[i * 8 + 2 * lane] = rl;
        Ho4[i * 8 + 2 * lane + 1] = rh;
    }
}

// ---------------- MLP head: block = 64 nodes; wave = hidden-chunk (uniform -> scalar weights) ----------------
__global__ __launch_bounds__(256) void mlp_kernel(
    const float* __restrict__ Hin, const float* __restrict__ Wd1, const float* __restrict__ bd1,
    const float* __restrict__ Wd2, const float* __restrict__ bd2, float* __restrict__ out) {
    const int lane = threadIdx.x & 63;
    const int chunk = __builtin_amdgcn_readfirstlane(threadIdx.x >> 6);   // 0..3, wave-uniform
    const int nb = blockIdx.x * 64;
    int node = nb + lane;
    int nclamp = node < NN ? node : NN - 1;

    float h[32];
    const float4* H4 = reinterpret_cast<const float4*>(Hin);
#pragma unroll
    for (int r = 0; r < 8; ++r) {
        float4 t = H4[nclamp * 8 + r];
        h[4 * r] = t.x; h[4 * r + 1] = t.y; h[4 * r + 2] = t.z; h[4 * r + 3] = t.w;
    }

    float o0 = 0.f, o1 = 0.f, o2 = 0.f, o3 = 0.f;
    const int dbase = chunk * 64;
    for (int t = 0; t < 4; ++t) {                    // 16-wide subtiles of this wave's 64 hidden units
        float acc[16];
#pragma unroll
        for (int j = 0; j < 16; ++j) acc[j] = bd1[dbase + t * 16 + j];
#pragma unroll 8
        for (int k = 0; k < 32; ++k) {
            const float* wr = Wd1 + k * DDd + dbase + t * 16;
#pragma unroll
            for (int j = 0; j < 16; ++j) acc[j] = fmaf(h[k], wr[j], acc[j]);
        }
#pragma unroll
        for (int j = 0; j < 16; ++j) {
            float hd = acc[j];
            hd = hd > 0.f ? hd : 0.01f * hd;
            int d = dbase + t * 16 + j;
            o0 = fmaf(hd, Wd2[d * 4 + 0], o0);
            o1 = fmaf(hd, Wd2[d * 4 + 1], o1);
            o2 = fmaf(hd, Wd2[d * 4 + 2], o2);
            o3 = fmaf(hd, Wd2[d * 4 + 3], o3);
        }
    }

    __shared__ float4 red[4][64];
    red[chunk][lane] = make_float4(o0, o1, o2, o3);
    __syncthreads();
    if (threadIdx.x < 64 && nb + (int)threadIdx.x < NN) {
        float4 r0 = red[0][threadIdx.x], r1 = red[1][threadIdx.x];
        float4 r2 = red[2][threadIdx.x], r3 = red[3][threadIdx.x];
        float4 o;
        o.x = r0.x + r1.x + r2.x + r3.x + bd2[0];
        o.y = r0.y + r1.y + r2.y + r3.y + bd2[1];
        o.z = r0.z + r1.z + r2.z + r3.z + bd2[2];
        o.w = r0.w + r1.w + r2.w + r3.w + bd2[3];
        reinterpret_cast<float4*>(out)[nb + threadIdx.x] = o;
    }
}

extern "C" void kernel_launch(void* const* d_in, const int* in_sizes, int n_in,
                              void* d_out, int out_size, void* d_ws, size_t ws_size,
                              hipStream_t stream) {
    const float* x    = (const float*)d_in[0];
    const void*  eraw = d_in[1];
    const float* ea   = (const float*)d_in[2];
    const float* Wl0  = (const float*)d_in[3];
    const float* bl0  = (const float*)d_in[4];
    const float* Wr0  = (const float*)d_in[5];
    const float* br0  = (const float*)d_in[6];
    const float* We0  = (const float*)d_in[7];
    const float* att0 = (const float*)d_in[8];
    const float* bo0  = (const float*)d_in[9];
    const float* Wl   = (const float*)d_in[10];
    const float* bl   = (const float*)d_in[11];
    const float* Wr   = (const float*)d_in[12];
    const float* br   = (const float*)d_in[13];
    const float* We   = (const float*)d_in[14];
    const float* att  = (const float*)d_in[15];
    const float* bo   = (const float*)d_in[16];
    const float* Wd1  = (const float*)d_in[17];
    const float* bd1  = (const float*)d_in[18];
    const float* Wd2  = (const float*)d_in[19];
    const float* bd2  = (const float*)d_in[20];
    float* out = (float*)d_out;

    char* p = (char*)d_ws;
    auto alloc = [&](size_t bytes) { void* r = (void*)p; p += (bytes + 255) & ~(size_t)255; return r; };
    int*       EI     = (int*)alloc((size_t)2 * EE * 4);
    int*       counts = (int*)alloc((size_t)(NN + 1) * 4);
    int*       roff   = (int*)alloc((size_t)(NN + 1) * 4);
    int*       bsum   = (int*)alloc(256 * 4);
    int*       boff   = (int*)alloc(256 * 4);
    int*       cursor = (int*)alloc((size_t)NN * 4);
    long long* ce     = (long long*)alloc((size_t)EE * 8);
    int*       flag   = (int*)alloc(256);
    float*     XLb    = (float*)alloc((size_t)NN * HCc * 4);
    float*     XRb    = (float*)alloc((size_t)NN * HCc * 4);
    float*     NLn    = (float*)alloc((size_t)NN * 4 * 4);
    float*     NRn    = (float*)alloc((size_t)NN * 4 * 4);
    float*     HA     = (float*)alloc((size_t)NN * DHc * 4);
    float*     HB     = (float*)alloc((size_t)NN * DHc * 4);

    (void)hipMemsetAsync(counts, 0, (size_t)(NN + 1) * 4, stream);
    (void)hipMemsetAsync(cursor, 0, (size_t)NN * 4, stream);
    (void)hipMemsetAsync(flag, 0, 4, stream);

    detect_kernel<<<1, 256, 0, stream>>>((const unsigned int*)eraw, 8192, flag);
    convert_count_kernel<<<(2 * EE + 255) / 256, 256, 0, stream>>>(eraw, flag, EI, counts);
    const int M = NN + 1;
    const int NBLK = (M + 255) / 256;
    scanA_kernel<<<NBLK, 256, 0, stream>>>(counts, roff, bsum, M);
    scanB_kernel<<<1, 256, 0, stream>>>(bsum, boff, NBLK);
    scanC_kernel<<<NBLK, 256, 0, stream>>>(roff, boff, M);
    fill_kernel<<<(EE + 255) / 256, 256, 0, stream>>>(EI, roff, cursor, ce);
    sort_kernel<<<(NN + 255) / 256, 256, 0, stream>>>(roff, ce);

    const int gT = (NN + 15) / 16;
    const int gG = (NN + 3) / 4;

    // layer 0
    transform_kernel<DFi><<<gT, 128, 0, stream>>>(x, Wl0, bl0, Wr0, br0, XLb, XRb, NLn, NRn);
    gat_kernel<<<gG, 256, 0, stream>>>(XLb, XRb, NLn, NRn, roff, ce, ea, We0, att0, bo0, HA);
    // layer 1
    transform_kernel<DHc><<<gT, 128, 0, stream>>>(HA, Wl, bl, Wr, br, XLb, XRb, NLn, NRn);
    gat_kernel<<<gG, 256, 0, stream>>>(XLb, XRb, NLn, NRn, roff, ce, ea, We, att, bo, HB);
    // layer 2
    transform_kernel<DHc><<<gT, 128, 0, stream>>>(HB, Wl + DHc * HCc, bl + HCc, Wr + DHc * HCc, br + HCc,
                                                  XLb, XRb, NLn, NRn);
    gat_kernel<<<gG, 256, 0, stream>>>(XLb, XRb, NLn, NRn, roff, ce, ea, We + DEe * HCc,
                                       att + Hh * DHc, bo + DHc, HA);
    // MLP head
    mlp_kernel<<<(NN + 63) / 64, 256, 0, stream>>>(HA, Wd1, bd1, Wd2, bd2, out);
}